// Round 1
// 236.897 us; speedup vs baseline: 1.0035x; 1.0035x over previous
//
#include <hip/hip_runtime.h>

// FastIMDCT4: B=32, T=1024, n_fft=2048, hop=1024.
// out[b, q*1024+r] = frames[b,q,1024+r] + frames[b,q+1,r], q in [0,1023)
// frames[m] = sign[m]*window[m]/512 * inter[post[m]];  inter from 512-pt FFT.
//
// R3: 8-wave blocks, 7 chunks/block, 8 register-resident 512-pt FFTs -> LDS,
//     one barrier, cooperative extraction. (82.9 us/dispatch, VALUBusy 75%)
// R4: kill the VALU bottleneck seen in rocprof (VALU-bound, HBM only 40%):
//     - LDS twiddle tables (conflict-free layouts), ZERO sin/cos in the FFT
//       (was 58 quarter-rate trans ops/lane ~ 23% of wave VALU time)
//     - cross-lane DIT restructured: twiddle pre-scale (lo-lane identity baked
//       into the table) + sign-FMA combine; removes per-reg cndmask chains
//     - extraction: postmap/window/offsets hoisted out of the chunk loop
//     LDS = 32768 (frames) + 4096 (T1) + 2560 (TS) + 512 (TM) + 512 (TPOST)
//         = 40448 B -> still 4 blocks/CU (160 KB).

#define CHUNKS 1023
#define CPB 7            // chunks per block
#define BPB 147          // blocks per batch: ceil(1023/7)

__device__ __forceinline__ float2 cmul(float2 a, float2 b) {
    return make_float2(a.x * b.x - a.y * b.y, a.x * b.y + a.y * b.x);
}
__device__ __forceinline__ float2 cadd(float2 a, float2 b) {
    return make_float2(a.x + b.x, a.y + b.y);
}
__device__ __forceinline__ float2 csub(float2 a, float2 b) {
    return make_float2(a.x - b.x, a.y - b.y);
}
// (cos,sin) of 2*pi*rev — v_cos_f32/v_sin_f32 take revolutions; |rev| < 1 here.
__device__ __forceinline__ float2 twid(float rev) {
    return make_float2(__builtin_amdgcn_cosf(rev), __builtin_amdgcn_sinf(rev));
}

// post[] / sign[] closed forms (verified R1/R2: absmax 9.8e-4):
__device__ __forceinline__ void postmap(int m, int& p, float& sgn) {
    bool even = ((m & 1) == 0);
    if (m < 512)       p = even ? (m + 512)  : (512 - m);
    else if (m < 1536) p = even ? (m - 511)  : (1535 - m);
    else               p = even ? (m - 1536) : (2560 - m);
    float s1 = even ? 1.0f : -1.0f;
    sgn = (m < 1536) ? s1 : -s1;
}

__device__ __forceinline__ int brev3(int r) {
    return ((r & 1) << 2) | (r & 2) | ((r >> 2) & 1);
}

// 512-pt FFT of one frame; writes split planes: planes[0..512)=Re, [512..1024)=Im.
// All twiddles come from LDS tables (no transcendentals here).
__device__ __forceinline__ void fft_frame(const float* __restrict__ row, int lane,
                                          float* __restrict__ planes,
                                          const float2* __restrict__ T1,
                                          const float2* __restrict__ TS,
                                          const float2* __restrict__ TM,
                                          const float2* __restrict__ TPOST) {
    const float2* row2 = (const float2*)row;
    const int rlane = (int)(__brev((unsigned)lane) >> 26);  // brev6(lane)

    // Load: reg r holds sample pair at k = 64*r + rlane (bit-reversed n2 across lanes).
    float2 v[8];
    #pragma unroll
    for (int r = 0; r < 8; ++r) v[r] = row2[64 * r + rlane];

    // c[r] = tw[k] * (row[2k] + i*row[1023-2k]); imag element lives in
    // lane^63's v[7-r].y. tw[k] = T1[k] (conflict-free: lane-permutation read).
    float2 c[8];
    #pragma unroll
    for (int r = 0; r < 8; ++r) {
        float im = __shfl_xor(v[7 - r].y, 63);
        float2 tw = T1[64 * r + rlane];
        c[r] = cmul(tw, make_float2(v[r].x, im));
    }

    // ---- radix-8 DIF in registers (natural in, bitrev3 out) ----
    const float RH = 0.70710678118654752f;
    {   // stage 1 (half=4)
        float2 u0 = c[0], u1 = c[1], u2 = c[2], u3 = c[3];
        float2 l0 = c[4], l1 = c[5], l2 = c[6], l3 = c[7];
        float2 t1 = csub(u1, l1), t2 = csub(u2, l2), t3 = csub(u3, l3);
        c[0] = cadd(u0, l0); c[4] = csub(u0, l0);
        c[1] = cadd(u1, l1); c[5] = cmul(make_float2(RH, -RH), t1);
        c[2] = cadd(u2, l2); c[6] = make_float2(t2.y, -t2.x);           // * -i
        c[3] = cadd(u3, l3); c[7] = cmul(make_float2(-RH, -RH), t3);
    }
    #pragma unroll
    for (int b = 0; b < 8; b += 4) {  // stage 2 (half=2)
        float2 u0 = c[b], u1 = c[b + 1], d0 = c[b + 2], d1 = c[b + 3];
        float2 t = csub(u1, d1);
        c[b] = cadd(u0, d0);
        c[b + 2] = csub(u0, d0);
        c[b + 1] = cadd(u1, d1);
        c[b + 3] = make_float2(t.y, -t.x);                              // * -i
    }
    #pragma unroll
    for (int b = 0; b < 8; b += 2) {  // stage 3 (half=1)
        float2 u = c[b], d = c[b + 1];
        c[b] = cadd(u, d); c[b + 1] = csub(u, d);
    }

    // ---- mid twiddle: reg r holds y[k1=brev3(r)]; z = y * W512^{rlane*k1}.
    // Power chain of w = TM[rlane] = W512^rlane (k1 order 1..7 -> regs 4,2,6,1,5,3,7).
    {
        float2 w = TM[rlane];
        float2 wc = w;
        c[4] = cmul(wc, c[4]);                    // w^1
        wc = cmul(wc, w); c[2] = cmul(wc, c[2]);  // w^2
        wc = cmul(wc, w); c[6] = cmul(wc, c[6]);  // w^3
        wc = cmul(wc, w); c[1] = cmul(wc, c[1]);  // w^4
        wc = cmul(wc, w); c[5] = cmul(wc, c[5]);  // w^5
        wc = cmul(wc, w); c[3] = cmul(wc, c[3]);  // w^6
        wc = cmul(wc, w); c[7] = cmul(wc, c[7]);  // w^7
    }

    // ---- cross-lane 64-pt radix-2 DIT (bitrev in across lanes, natural out).
    // Pre-scaled twiddle: hi lane multiplies its value by w BEFORE the exchange
    // (TS entry is identity on lo lanes), then c = oth + sgn*c (2 FMAs).
    //   lo: c_lo + (w*c_hi) = E + wO ;  hi: (1*c_lo) - w*c_hi = E - wO.
    #pragma unroll
    for (int s = 1; s <= 6; ++s) {
        const int half = 1 << (s - 1);
        const float sgn = (lane & half) ? -1.0f : 1.0f;
        float2 weff = make_float2(1.0f, 0.0f);
        if (s >= 2) weff = TS[(s - 2) * 64 + lane];  // conflict-free stride-8B
        #pragma unroll
        for (int r = 0; r < 8; ++r) {
            float2 cp = (s >= 2) ? cmul(weff, c[r]) : c[r];
            float ox = __shfl_xor(cp.x, half);
            float oy = __shfl_xor(cp.y, half);
            c[r] = make_float2(fmaf(sgn, cp.x, ox), fmaf(sgn, cp.y, oy));
        }
    }

    // ---- post twiddle + reorder to natural k = j + 8*lane; store split planes.
    // W2048^{(j+8*lane)+0.125} = TPOST[lane] * K[j], K[j]=W2048^j compile-time.
    const float KC[8] = {1.0f,
                         0.99999529380957619f, 0.99998117528260111f,
                         0.99995764455196390f, 0.99992470183914450f,
                         0.99988234745421256f, 0.99983058179582340f,
                         0.99976940535121528f};
    const float KS[8] = {0.0f,
                         -0.0030679567629659761f, -0.0061358846491544753f,
                         -0.0092037547820598194f, -0.0122715382857199261f,
                         -0.0153392062849881011f, -0.0184067299058048209f,
                         -0.0214738704100051880f};
    float2 base = TPOST[lane];
    float2 d[8];
    #pragma unroll
    for (int j = 0; j < 8; ++j) {
        float2 tw = (j == 0) ? base : cmul(base, make_float2(KC[j], KS[j]));
        d[j] = cmul(tw, c[brev3(j)]);   // brev3 is an involution
    }
    float4 r0 = make_float4(d[0].x, d[1].x, d[2].x, d[3].x);
    float4 r1 = make_float4(d[4].x, d[5].x, d[6].x, d[7].x);
    float4 i0 = make_float4(d[0].y, d[1].y, d[2].y, d[3].y);
    float4 i1 = make_float4(d[4].y, d[5].y, d[6].y, d[7].y);
    *(float4*)(planes + 8 * lane)           = r0;
    *(float4*)(planes + 8 * lane + 4)       = r1;
    *(float4*)(planes + 512 + 8 * lane)     = i0;
    *(float4*)(planes + 512 + 8 * lane + 4) = i1;
}

__global__ __launch_bounds__(512) void imdct_kernel(
        const float* __restrict__ signal,
        const float* __restrict__ window,
        float* __restrict__ out) {
    __shared__ float lds[8][1024];   // 8 frames x (Re[512] | Im[512]) = 32 KB
    __shared__ float2 T1[512];       // W2048^{k+0.125}, k=0..511           (4 KB)
    __shared__ float2 TS[5][64];     // stage s=2..6 twiddles, lane-indexed (2.5 KB)
    __shared__ float2 TM[64];        // W512^l                              (0.5 KB)
    __shared__ float2 TPOST[64];     // W2048^{8l+0.125}                    (0.5 KB)

    const int tid = threadIdx.x;
    const int lane = tid & 63;
    const int w = tid >> 6;

    // ---- table init: <=4 sincos per thread, once per block ----
    T1[tid] = twid(-((float)tid + 0.125f) * (1.0f / 2048.0f));
    if (tid < 64) {
        TM[tid]    = twid(-(float)tid * (1.0f / 512.0f));
        TPOST[tid] = twid(-((float)(8 * tid) + 0.125f) * (1.0f / 2048.0f));
    }
    if (tid < 320) {
        // stage s' = si+2, half = 1<<(s'-1) = 2<<si, denom 2^{s'} = 4<<si.
        // lo-lane entries are identity: the hi?w:1 select is baked in here.
        const int si = tid >> 6;
        const int l = tid & 63;
        const int half = 2 << si;
        float2 wv = make_float2(1.0f, 0.0f);
        if (l & half) wv = twid(-(float)(l & (half - 1)) / (float)(4 << si));
        TS[si][l] = wv;
    }
    __syncthreads();

    const int bid = blockIdx.x;
    const int b = bid / BPB;
    const int cblk = bid - b * BPB;
    const int q0 = cblk * CPB;          // first chunk of this block

    // Phase 1: each wave FFTs one frame (q0+w) into its LDS slot.
    const int f = q0 + w;
    if (f <= 1023) {
        fft_frame(signal + (size_t)(b * 1024 + f) * 1024, lane, &lds[w][0],
                  &T1[0], &TS[0][0], &TM[0], &TPOST[0]);
    }
    __syncthreads();

    // Phase 2: cooperative extraction. Everything except the 4 LDS reads and
    // the store is chunk-invariant -> hoisted.
    float* orow_base = out + (size_t)b * (CHUNKS * 1024);
    const int r = 2 * tid;               // element pair within a chunk

    int p00, p01, p10, p11; float s00, s01, s10, s11;
    postmap(1024 + r,     p00, s00);     // frame qj,   e=0
    postmap(1024 + r + 1, p01, s01);     // frame qj,   e=1
    postmap(r,            p10, s10);     // frame qj+1, e=0
    postmap(r + 1,        p11, s11);     // frame qj+1, e=1
    const float2 wh = *(const float2*)(window + 1024 + r);
    const float2 wl = *(const float2*)(window + r);
    const float a00 = s00 * wh.x * (1.0f / 512.0f);
    const float a01 = s01 * wh.y * (1.0f / 512.0f);
    const float a10 = s10 * wl.x * (1.0f / 512.0f);
    const float a11 = s11 * wl.y * (1.0f / 512.0f);
    const int o00 = (p00 & 1) * 512 + (p00 >> 1);
    const int o01 = (p01 & 1) * 512 + (p01 >> 1);
    const int o10 = (p10 & 1) * 512 + (p10 >> 1);
    const int o11 = (p11 & 1) * 512 + (p11 >> 1);

    #pragma unroll
    for (int j = 0; j < CPB; ++j) {
        const int qj = q0 + j;
        if (qj > 1022) break;            // block-uniform
        const float* f0 = &lds[j][0];
        const float* f1 = &lds[j + 1][0];
        float2 o;
        o.x = a00 * f0[o00] + a10 * f1[o10];
        o.y = a01 * f0[o01] + a11 * f1[o11];
        *(float2*)(orow_base + (size_t)qj * 1024 + r) = o;
    }
}

extern "C" void kernel_launch(void* const* d_in, const int* in_sizes, int n_in,
                              void* d_out, int out_size, void* d_ws, size_t ws_size,
                              hipStream_t stream) {
    const float* signal = (const float*)d_in[0];
    const float* window = (const float*)d_in[1];
    float* out = (float*)d_out;
    // 32 batches x 147 blocks (7 chunks each), 512 threads (8 waves) per block
    imdct_kernel<<<dim3(32 * BPB), dim3(512), 0, stream>>>(signal, window, out);
}

// Round 2
// 236.362 us; speedup vs baseline: 1.0058x; 1.0023x over previous
//
#include <hip/hip_runtime.h>

// FastIMDCT4: B=32, T=1024, n_fft=2048, hop=1024.
// out[b, q*1024+r] = frames[b,q,1024+r] + frames[b,q+1,r], q in [0,1023)
// frames[m] = sign[m]*window[m]/512 * inter[post[m]];  inter from 512-pt FFT.
//
// R3: 8-wave blocks, 7 chunks/block, register 512-pt FFT (radix-8 regs x 64-pt
//     shfl DIT) -> LDS, barrier, cooperative extraction. 82.9us, VALUBusy 75%.
// R4: LDS twiddle tables, FMA butterflies. VALUBusy 75->48% but dur unchanged
//     -> kernel is DS-pipe bound: ~1210 DS wave-instrs/block (96 butterfly
//     shuffles/FFT = ds_swizzle on CDNA!) + 4.9M conflict cycles (bit-reversed
//     T1 reads, 32B-stride b128 stores).
// R5: 8x8x8 FFT: three in-register radix-8 stages + TWO barrier-free per-wave
//     LDS transposes (XOR-swizzled, conflict-free) replace the 96 shuffles.
//     Natural-order b32 final stores (conflict-free) keep R4's verified
//     extraction untouched. DS ops/FFT: 123 -> 60, conflicts ~0.
//     LDS = 32768 + 1600 tables = 34368 B -> 4 blocks/CU.

#define CHUNKS 1023
#define CPB 7            // chunks per block
#define BPB 147          // blocks per batch: ceil(1023/7)

__device__ __forceinline__ float2 cmul(float2 a, float2 b) {
    return make_float2(a.x * b.x - a.y * b.y, a.x * b.y + a.y * b.x);
}
__device__ __forceinline__ float2 cadd(float2 a, float2 b) {
    return make_float2(a.x + b.x, a.y + b.y);
}
__device__ __forceinline__ float2 csub(float2 a, float2 b) {
    return make_float2(a.x - b.x, a.y - b.y);
}
// (cos,sin) of 2*pi*rev — v_cos_f32/v_sin_f32 take revolutions; |rev| < 1 here.
__device__ __forceinline__ float2 twid(float rev) {
    return make_float2(__builtin_amdgcn_cosf(rev), __builtin_amdgcn_sinf(rev));
}

// post[] / sign[] closed forms (verified R1/R2: absmax 9.8e-4):
__device__ __forceinline__ void postmap(int m, int& p, float& sgn) {
    bool even = ((m & 1) == 0);
    if (m < 512)       p = even ? (m + 512)  : (512 - m);
    else if (m < 1536) p = even ? (m - 511)  : (1535 - m);
    else               p = even ? (m - 1536) : (2560 - m);
    float s1 = even ? 1.0f : -1.0f;
    sgn = (m < 1536) ? s1 : -s1;
}

__device__ __forceinline__ int brev3(int r) {
    return ((r & 1) << 2) | (r & 2) | ((r >> 2) & 1);
}

// 8-pt DFT, natural input order, output digit d lives in reg brev3(d).
// (DIF structure; verified as part of R3/R4 end-to-end.)
__device__ __forceinline__ void radix8(float2 c[8]) {
    const float RH = 0.70710678118654752f;
    {   // stage 1 (half=4)
        float2 u0 = c[0], u1 = c[1], u2 = c[2], u3 = c[3];
        float2 l0 = c[4], l1 = c[5], l2 = c[6], l3 = c[7];
        float2 t1 = csub(u1, l1), t2 = csub(u2, l2), t3 = csub(u3, l3);
        c[0] = cadd(u0, l0); c[4] = csub(u0, l0);
        c[1] = cadd(u1, l1); c[5] = cmul(make_float2(RH, -RH), t1);
        c[2] = cadd(u2, l2); c[6] = make_float2(t2.y, -t2.x);           // * -i
        c[3] = cadd(u3, l3); c[7] = cmul(make_float2(-RH, -RH), t3);
    }
    #pragma unroll
    for (int b = 0; b < 8; b += 4) {  // stage 2 (half=2)
        float2 u0 = c[b], u1 = c[b + 1], d0 = c[b + 2], d1 = c[b + 3];
        float2 t = csub(u1, d1);
        c[b] = cadd(u0, d0);
        c[b + 2] = csub(u0, d0);
        c[b + 1] = cadd(u1, d1);
        c[b + 3] = make_float2(t.y, -t.x);                              // * -i
    }
    #pragma unroll
    for (int b = 0; b < 8; b += 2) {  // stage 3 (half=1)
        float2 u = c[b], d = c[b + 1];
        c[b] = cadd(u, d); c[b + 1] = csub(u, d);
    }
}

// Apply w^digit to each reg (digit(r) = brev3(r)): power chain in digit order.
__device__ __forceinline__ void midchain(float2 c[8], float2 w) {
    float2 wc = w;
    c[4] = cmul(wc, c[4]);                    // digit 1
    wc = cmul(wc, w); c[2] = cmul(wc, c[2]);  // digit 2
    wc = cmul(wc, w); c[6] = cmul(wc, c[6]);  // digit 3
    wc = cmul(wc, w); c[1] = cmul(wc, c[1]);  // digit 4
    wc = cmul(wc, w); c[5] = cmul(wc, c[5]);  // digit 5
    wc = cmul(wc, w); c[3] = cmul(wc, c[3]);  // digit 6
    wc = cmul(wc, w); c[7] = cmul(wc, c[7]);  // digit 7
}

// W32^r = W2048^{64r} = exp(-2*pi*i*r/32), exact compile-time constants.
#define K32_DECL \
    const float K32C[8] = {1.0f, 0.98078528040323044913f, 0.92387953251128675613f, \
                           0.83146961230254523708f, 0.70710678118654752440f,       \
                           0.55557023301960222474f, 0.38268343236508977173f,       \
                           0.19509032201612826785f};                               \
    const float K32S[8] = {0.0f, -0.19509032201612826785f, -0.38268343236508977173f,\
                           -0.55557023301960222474f, -0.70710678118654752440f,     \
                           -0.83146961230254523708f, -0.92387953251128675613f,     \
                           -0.98078528040323044913f};

// 512-pt FFT of one frame; writes split planes: planes[0..512)=Re, [512..1024)=Im
// (natural k order — same layout R4's extraction was verified against).
//
// Decomposition: n = 64*n1 + n2, n2 = 8*m1 + m0; k = k1 + 8*j1 + 64*j2.
//   stage1: radix-8 over n1 (regs)        -> k1;  twiddle W512^{n2*k1}
//   stage2: radix-8 over m1 (regs, redis) -> j1;  twiddle W64^{m0*j1}
//   stage3: radix-8 over m0 (regs, redis) -> j2;  post twiddle W2048^{k+1/8}
// Redistributes use the wave's own LDS slot (scratch aliases planes); within a
// wave DS ops execute in order, so no barrier is needed.
__device__ __forceinline__ void fft_frame(const float* __restrict__ row, int lane,
                                          float* __restrict__ planes,
                                          const float2* __restrict__ T1b,
                                          const float2* __restrict__ TM,
                                          const float2* __restrict__ TM2,
                                          const float2* __restrict__ TP2) {
    K32_DECL
    const float2* row2 = (const float2*)row;
    float2* scratch = (float2*)planes;
    const int lh = lane >> 3;   // m1 at load; k1 after redis-1
    const int ll = lane & 7;    // m0 at load; m0 then j1 later

    // Load: reg r = n1, lane = n2. Fully coalesced (512B/instr).
    float2 v[8];
    #pragma unroll
    for (int r = 0; r < 8; ++r) v[r] = row2[64 * r + lane];

    // Pre: c_n = W2048^{n+1/8} * (row[2n] + i*row[1023-2n]); imag lives in
    // lane^63's v[7-r].y. W2048^{64r+lane+1/8} = T1b[lane] * K32[r].
    float2 base = T1b[lane];
    float2 c[8];
    #pragma unroll
    for (int r = 0; r < 8; ++r) {
        float im = __shfl_xor(v[7 - r].y, 63);
        float2 tw = (r == 0) ? base : cmul(base, make_float2(K32C[r], K32S[r]));
        c[r] = cmul(tw, make_float2(v[r].x, im));
    }

    // ---- stage 1: radix-8 over n1 -> digit k1 (reg brev3(k1)) ----
    radix8(c);
    midchain(c, TM[lane]);                       // * W512^{n2*k1}, n2 = lane

    // ---- redistribute 1: (k1 in regs, lane=(m1,m0)) -> (m1 in regs, lane=(k1,m0))
    // scratch idx(k1,m1,m0) = k1*64 + (m1^k1)*8 + m0.
    // Writes: contiguous-permuted 64-block per instr (conflict-free).
    // Reads (fixed m1): quarter-wave k1 parity flips the 16-bank group -> free.
    #pragma unroll
    for (int r = 0; r < 8; ++r) {
        const int q = brev3(r);                  // k1 digit held by reg r
        scratch[q * 64 + ((lh ^ q)) * 8 + ll] = c[r];
    }
    asm volatile("" ::: "memory");
    #pragma unroll
    for (int r = 0; r < 8; ++r)
        c[r] = scratch[lh * 64 + ((r ^ lh)) * 8 + ll];   // now lh=k1, ll=m0

    // ---- stage 2: radix-8 over m1 -> digit j1 ----
    radix8(c);
    midchain(c, TM2[ll]);                        // * W64^{m0*j1}, m0 = ll

    // ---- redistribute 2: (j1 in regs, lane=(k1,m0)) -> (m0 in regs, lane=(k1,j1))
    // scratch idx(k1,j1,m0) = k1*64 + (j1^k1)*8 + (m0^j1).
    // Both write and read conflict-free per quarter-wave (k1 flips bank group).
    #pragma unroll
    for (int r = 0; r < 8; ++r) {
        const int j1 = brev3(r);
        scratch[lh * 64 + ((j1 ^ lh)) * 8 + (ll ^ j1)] = c[r];
    }
    asm volatile("" ::: "memory");
    #pragma unroll
    for (int r = 0; r < 8; ++r)
        c[r] = scratch[lh * 64 + ((ll ^ lh)) * 8 + (r ^ ll)];  // now ll = j1

    // ---- stage 3: radix-8 over m0 -> digit j2 ----
    radix8(c);

    // ---- post twiddle + natural-order store: k = 64*j2 + 8*j1 + k1 ----
    // W2048^{k+1/8} = K32[j2] * TP2[lane], TP2[l] = W2048^{8*(l&7)+(l>>3)+1/8}.
    // Store: per instr, addresses are a permutation of one 64-float block
    // (conflict-free b32). DS writes cannot pass the reads above (in-order).
    float2 base2 = TP2[lane];
    const int kbase = 8 * ll + lh;               // 8*j1 + k1
    #pragma unroll
    for (int j = 0; j < 8; ++j) {
        float2 tw = (j == 0) ? base2 : cmul(base2, make_float2(K32C[j], K32S[j]));
        float2 dv = cmul(tw, c[brev3(j)]);       // reg brev3(j) holds digit j
        planes[64 * j + kbase]       = dv.x;
        planes[512 + 64 * j + kbase] = dv.y;
    }
}

__global__ __launch_bounds__(512) void imdct_kernel(
        const float* __restrict__ signal,
        const float* __restrict__ window,
        float* __restrict__ out) {
    __shared__ float lds[8][1024];   // 8 frames x (Re[512] | Im[512]) = 32 KB
    __shared__ float2 T1b[64];       // W2048^{l+1/8}
    __shared__ float2 TM[64];        // W512^{l}
    __shared__ float2 TP2[64];       // W2048^{8*(l&7)+(l>>3)+1/8}
    __shared__ float2 TM2[8];        // W64^{l}

    const int tid = threadIdx.x;
    const int lane = tid & 63;
    const int w = tid >> 6;

    // ---- table init: 3 sincos on 64 threads, once per block ----
    if (tid < 64) {
        T1b[tid] = twid(-((float)tid + 0.125f) * (1.0f / 2048.0f));
        TM[tid]  = twid(-(float)tid * (1.0f / 512.0f));
        TP2[tid] = twid(-((float)(8 * (tid & 7) + (tid >> 3)) + 0.125f) * (1.0f / 2048.0f));
    }
    if (tid < 8) TM2[tid] = twid(-(float)tid * (1.0f / 64.0f));
    __syncthreads();

    const int bid = blockIdx.x;
    const int b = bid / BPB;
    const int cblk = bid - b * BPB;
    const int q0 = cblk * CPB;          // first chunk of this block

    // Phase 1: each wave FFTs one frame (q0+w) into its LDS slot.
    const int f = q0 + w;
    if (f <= 1023) {
        fft_frame(signal + (size_t)(b * 1024 + f) * 1024, lane, &lds[w][0],
                  T1b, TM, TM2, TP2);
    }
    __syncthreads();

    // Phase 2: cooperative extraction (verified R4). Everything except the 4
    // LDS reads and the store is chunk-invariant -> hoisted. All four offset
    // streams are lane-contiguous -> conflict-free b32 reads.
    float* orow_base = out + (size_t)b * (CHUNKS * 1024);
    const int r = 2 * tid;               // element pair within a chunk

    int p00, p01, p10, p11; float s00, s01, s10, s11;
    postmap(1024 + r,     p00, s00);     // frame qj,   e=0
    postmap(1024 + r + 1, p01, s01);     // frame qj,   e=1
    postmap(r,            p10, s10);     // frame qj+1, e=0
    postmap(r + 1,        p11, s11);     // frame qj+1, e=1
    const float2 wh = *(const float2*)(window + 1024 + r);
    const float2 wl = *(const float2*)(window + r);
    const float a00 = s00 * wh.x * (1.0f / 512.0f);
    const float a01 = s01 * wh.y * (1.0f / 512.0f);
    const float a10 = s10 * wl.x * (1.0f / 512.0f);
    const float a11 = s11 * wl.y * (1.0f / 512.0f);
    const int o00 = (p00 & 1) * 512 + (p00 >> 1);
    const int o01 = (p01 & 1) * 512 + (p01 >> 1);
    const int o10 = (p10 & 1) * 512 + (p10 >> 1);
    const int o11 = (p11 & 1) * 512 + (p11 >> 1);

    #pragma unroll
    for (int j = 0; j < CPB; ++j) {
        const int qj = q0 + j;
        if (qj > 1022) break;            // block-uniform
        const float* f0 = &lds[j][0];
        const float* f1 = &lds[j + 1][0];
        float2 o;
        o.x = a00 * f0[o00] + a10 * f1[o10];
        o.y = a01 * f0[o01] + a11 * f1[o11];
        *(float2*)(orow_base + (size_t)qj * 1024 + r) = o;
    }
}

extern "C" void kernel_launch(void* const* d_in, const int* in_sizes, int n_in,
                              void* d_out, int out_size, void* d_ws, size_t ws_size,
                              hipStream_t stream) {
    const float* signal = (const float*)d_in[0];
    const float* window = (const float*)d_in[1];
    float* out = (float*)d_out;
    // 32 batches x 147 blocks (7 chunks each), 512 threads (8 waves) per block
    imdct_kernel<<<dim3(32 * BPB), dim3(512), 0, stream>>>(signal, window, out);
}